// Round 1
// baseline (541.408 us; speedup 1.0000x reference)
//
#include <hip/hip_runtime.h>
#include <hip/hip_bf16.h>
#include <stdint.h>

// ---------------------------------------------------------------------------
// SupervisedTEMTransition: logits = clip(g + routed_transition(g), +-1) @ W^T + b
//   B=16384, G_TOTAL=768 (modules 256,256,128,128), A=4, NUM_STATES=4096
// Strategy:
//   prep:   gather emb[state] -> A1 bf16 [16384x768]; W_cls -> Wb bf16; D* -> Db bf16
//   trans:  per module f: delta_all = G_f @ reshape(D_f,[4n,n])^T  (bf16 MFMA GEMM,
//           N=4n; epilogue keeps only the column block where a == action[row],
//           writes g_next fp32 to d_out part 2 and bf16 copy A2)
//   cls:    logits = A2 @ Wb^T + b  (bf16 MFMA GEMM, fp32 epilogue -> d_out part 1)
// GEMM core: 128x128 tile, BK=64, mfma_f32_16x16x32_bf16, 4 waves (2x2) with
// 4x4 float4 accumulators, global_load_lds width=16 staging, XOR-swizzled LDS.
// ---------------------------------------------------------------------------

typedef __attribute__((ext_vector_type(8))) short short8;   // 8 x bf16 (4 VGPRs)
typedef __attribute__((ext_vector_type(4))) float floatx4;  // MFMA C/D

__device__ __forceinline__ float bf2f(short s) {
    unsigned int u = ((unsigned int)(unsigned short)s) << 16;
    float f;
    __builtin_memcpy(&f, &u, 4);
    return f;
}
__device__ __forceinline__ short f2bf(float f) {  // round-to-nearest-even
    unsigned int u;
    __builtin_memcpy(&u, &f, 4);
    u = (u + 0x7FFFu + ((u >> 16) & 1u)) >> 16;
    return (short)u;
}

#define GLLDS16(g, l)                                                                     \
    __builtin_amdgcn_global_load_lds((const __attribute__((address_space(1))) void*)(g),  \
                                     (__attribute__((address_space(3))) void*)(l), 16, 0, 0)

// ---------------------------------------------------------------------------
// prep: one float4 per thread. Regions (float4 units):
//   A1 gather  : [0, 3145728)          16384*768/4
//   W_cls      : [3145728, 3932160)    4096*768/4
//   D0         : [3932160, 3997696)    4*256*256/4
//   D1         : [3997696, 4063232)
//   D2         : [4063232, 4079616)    4*128*128/4
//   D3         : [4079616, 4096000)
// ---------------------------------------------------------------------------
__global__ __launch_bounds__(256) void prep_kernel(
    const int* __restrict__ state, const float* __restrict__ emb,
    const float* __restrict__ W, const float* __restrict__ D0,
    const float* __restrict__ D1, const float* __restrict__ D2,
    const float* __restrict__ D3, short* __restrict__ A1,
    short* __restrict__ Wb, short* __restrict__ Db) {
    long e = (long)blockIdx.x * 256 + threadIdx.x;
    const float* src;
    short* dst;
    long di;
    if (e < 3145728L) {
        int b = (int)(e / 192);
        int cc = (int)(e % 192);
        int s = state[b];
        src = emb + (long)s * 768 + cc * 4;
        dst = A1; di = e;
    } else if (e < 3932160L) {
        long t = e - 3145728L;
        src = W + t * 4; dst = Wb; di = t;
    } else if (e < 3997696L) {
        long t = e - 3932160L;
        src = D0 + t * 4; dst = Db; di = t;
    } else if (e < 4063232L) {
        long t = e - 3997696L;
        src = D1 + t * 4; dst = Db + 262144; di = t;
    } else if (e < 4079616L) {
        long t = e - 4063232L;
        src = D2 + t * 4; dst = Db + 524288; di = t;
    } else {
        long t = e - 4079616L;
        src = D3 + t * 4; dst = Db + 589824; di = t;
    }
    float4 v = *(const float4*)src;
    union { ushort4 u4; short s4[4]; } o;
    o.s4[0] = f2bf(v.x); o.s4[1] = f2bf(v.y);
    o.s4[2] = f2bf(v.z); o.s4[3] = f2bf(v.w);
    *(ushort4*)(dst + di * 4) = o.u4;
}

// ---------------------------------------------------------------------------
// Transition GEMM. A: A1+module_off (row stride 768, K=n cols), Bm: Db_f [4n x n].
// Grid: (4n/128, 128). Epilogue: tile's action block = (bn*128)/n (exact: n
// is 128 or 256, so every 128-col tile lies inside one action block).
// ---------------------------------------------------------------------------
__global__ __launch_bounds__(256) void trans_gemm_kernel(
    const short* __restrict__ A, const short* __restrict__ Bm,
    const int* __restrict__ act, float* __restrict__ gnext,
    short* __restrict__ A2, int n, int K) {
    __shared__ short Ash[128 * 64];
    __shared__ short Bsh[128 * 64];
    const int tid = threadIdx.x;
    const int lane = tid & 63;
    const int w = tid >> 6;
    const int wm = w & 1, wn = w >> 1;
    const int bn = blockIdx.x, bm = blockIdx.y;
    const long arow0 = (long)bm * 128;
    const long brow0 = (long)bn * 128;
    const int lrow = lane & 15;
    const int q = lane >> 4;

    floatx4 acc[4][4] = {};

    for (int k0 = 0; k0 < K; k0 += 64) {
        #pragma unroll
        for (int it = 0; it < 4; ++it) {
            int c = it * 256 + tid;      // 16B chunk id: row = c/8, kchunk = c%8
            int r = c >> 3, cc = c & 7;
            int gc = cc ^ (r & 7);       // XOR swizzle (bank-conflict-free reads)
            GLLDS16(A + (arow0 + r) * 768 + k0 + gc * 8, &Ash[c * 8]);
            GLLDS16(Bm + (brow0 + r) * (long)n + k0 + gc * 8, &Bsh[c * 8]);
        }
        __syncthreads();
        #pragma unroll
        for (int kk = 0; kk < 2; ++kk) {
            short8 af[4], bv[4];
            #pragma unroll
            for (int mi = 0; mi < 4; ++mi) {
                int rr = wm * 64 + mi * 16 + lrow;
                int ch = (kk * 4 + q) ^ (rr & 7);
                af[mi] = *(const short8*)&Ash[rr * 64 + ch * 8];
            }
            #pragma unroll
            for (int ni = 0; ni < 4; ++ni) {
                int rr = wn * 64 + ni * 16 + lrow;
                int ch = (kk * 4 + q) ^ (rr & 7);
                bv[ni] = *(const short8*)&Bsh[rr * 64 + ch * 8];
            }
            #pragma unroll
            for (int mi = 0; mi < 4; ++mi)
                #pragma unroll
                for (int ni = 0; ni < 4; ++ni)
                    acc[mi][ni] = __builtin_amdgcn_mfma_f32_16x16x32_bf16(
                        af[mi], bv[ni], acc[mi][ni], 0, 0, 0);
        }
        __syncthreads();
    }

    const int tile_action = (bn * 128) / n;
    const int jb = bn * 128 - tile_action * n + wn * 64;  // module-local col base
    const int rowbase = bm * 128 + wm * 64;
    #pragma unroll
    for (int mi = 0; mi < 4; ++mi) {
        #pragma unroll
        for (int r = 0; r < 4; ++r) {
            int row = rowbase + mi * 16 + q * 4 + r;
            if (act[row] == tile_action) {
                #pragma unroll
                for (int ni = 0; ni < 4; ++ni) {
                    int jl = jb + ni * 16 + lrow;
                    long idx = (long)row * 768 + jl;
                    float g = bf2f(A[idx]);
                    float v = g + acc[mi][ni][r];
                    v = fminf(1.0f, fmaxf(-1.0f, v));
                    gnext[idx] = v;
                    A2[idx] = f2bf(v);
                }
            }
        }
    }
}

// ---------------------------------------------------------------------------
// Classifier GEMM: [16384x768] @ [4096x768]^T + bias -> fp32. Grid (32, 128).
// ---------------------------------------------------------------------------
__global__ __launch_bounds__(256) void cls_gemm_kernel(
    const short* __restrict__ A, const short* __restrict__ Bm,
    const float* __restrict__ bias, float* __restrict__ out) {
    __shared__ short Ash[128 * 64];
    __shared__ short Bsh[128 * 64];
    const int tid = threadIdx.x;
    const int lane = tid & 63;
    const int w = tid >> 6;
    const int wm = w & 1, wn = w >> 1;
    const int bn = blockIdx.x, bm = blockIdx.y;
    const long arow0 = (long)bm * 128;
    const long brow0 = (long)bn * 128;
    const int lrow = lane & 15;
    const int q = lane >> 4;

    floatx4 acc[4][4] = {};

    for (int k0 = 0; k0 < 768; k0 += 64) {
        #pragma unroll
        for (int it = 0; it < 4; ++it) {
            int c = it * 256 + tid;
            int r = c >> 3, cc = c & 7;
            int gc = cc ^ (r & 7);
            GLLDS16(A + (arow0 + r) * 768 + k0 + gc * 8, &Ash[c * 8]);
            GLLDS16(Bm + (brow0 + r) * 768 + k0 + gc * 8, &Bsh[c * 8]);
        }
        __syncthreads();
        #pragma unroll
        for (int kk = 0; kk < 2; ++kk) {
            short8 af[4], bv[4];
            #pragma unroll
            for (int mi = 0; mi < 4; ++mi) {
                int rr = wm * 64 + mi * 16 + lrow;
                int ch = (kk * 4 + q) ^ (rr & 7);
                af[mi] = *(const short8*)&Ash[rr * 64 + ch * 8];
            }
            #pragma unroll
            for (int ni = 0; ni < 4; ++ni) {
                int rr = wn * 64 + ni * 16 + lrow;
                int ch = (kk * 4 + q) ^ (rr & 7);
                bv[ni] = *(const short8*)&Bsh[rr * 64 + ch * 8];
            }
            #pragma unroll
            for (int mi = 0; mi < 4; ++mi)
                #pragma unroll
                for (int ni = 0; ni < 4; ++ni)
                    acc[mi][ni] = __builtin_amdgcn_mfma_f32_16x16x32_bf16(
                        af[mi], bv[ni], acc[mi][ni], 0, 0, 0);
        }
        __syncthreads();
    }

    const int rowbase = bm * 128 + wm * 64;
    const int colbase = bn * 128 + wn * 64;
    #pragma unroll
    for (int mi = 0; mi < 4; ++mi) {
        #pragma unroll
        for (int r = 0; r < 4; ++r) {
            int row = rowbase + mi * 16 + q * 4 + r;
            #pragma unroll
            for (int ni = 0; ni < 4; ++ni) {
                int col = colbase + ni * 16 + lrow;
                out[(long)row * 4096 + col] = acc[mi][ni][r] + bias[col];
            }
        }
    }
}

extern "C" void kernel_launch(void* const* d_in, const int* in_sizes, int n_in,
                              void* d_out, int out_size, void* d_ws, size_t ws_size,
                              hipStream_t stream) {
    const int* state  = (const int*)d_in[0];
    const int* act    = (const int*)d_in[1];
    const float* emb  = (const float*)d_in[2];
    const float* W    = (const float*)d_in[3];
    const float* bias = (const float*)d_in[4];
    const float* D0   = (const float*)d_in[5];
    const float* D1   = (const float*)d_in[6];
    const float* D2   = (const float*)d_in[7];
    const float* D3   = (const float*)d_in[8];

    float* logits = (float*)d_out;              // [16384 x 4096]
    float* gnext  = logits + 67108864L;         // [16384 x 768]

    short* A1 = (short*)d_ws;                   // g bf16        [16384 x 768]
    short* A2 = A1 + 12582912L;                 // g_next bf16   [16384 x 768]
    short* Wb = A2 + 12582912L;                 // W_cls bf16    [4096 x 768]
    short* Db = Wb + 3145728L;                  // D0|D1|D2|D3 bf16 (655360)

    prep_kernel<<<16000, 256, 0, stream>>>(state, emb, W, D0, D1, D2, D3, A1, Wb, Db);

    // module 0: n=256, off=0;  module 1: n=256, off=256
    trans_gemm_kernel<<<dim3(8, 128), 256, 0, stream>>>(A1, Db, act, gnext, A2, 256, 256);
    trans_gemm_kernel<<<dim3(8, 128), 256, 0, stream>>>(A1 + 256, Db + 262144, act,
                                                        gnext + 256, A2 + 256, 256, 256);
    // module 2: n=128, off=512;  module 3: n=128, off=640
    trans_gemm_kernel<<<dim3(4, 128), 256, 0, stream>>>(A1 + 512, Db + 524288, act,
                                                        gnext + 512, A2 + 512, 128, 128);
    trans_gemm_kernel<<<dim3(4, 128), 256, 0, stream>>>(A1 + 640, Db + 589824, act,
                                                        gnext + 640, A2 + 640, 128, 128);

    cls_gemm_kernel<<<dim3(32, 128), 256, 0, stream>>>(A2, Wb, bias, logits);
}